// Round 3
// baseline (1025.060 us; speedup 1.0000x reference)
//
#include <hip/hip_runtime.h>
#include <cstdint>
#include <cstddef>

#define DEV __device__ __forceinline__

typedef __attribute__((ext_vector_type(8))) short short8;
typedef __attribute__((ext_vector_type(4))) float floatx4;
typedef unsigned short u16;
typedef unsigned int u32;

union Frag { short8 s8; uint4 u4; uint2 u2[2]; u16 us[8]; };

DEV float b2f(u16 u) { union { float f; u32 i; } v; v.i = ((u32)u) << 16; return v.f; }
DEV u16 f2b(float f) {
  union { float f; u32 i; } v; v.f = f; u32 x = v.i;
  return (u16)((x + 0x7fffu + ((x >> 16) & 1u)) >> 16);
}
DEV floatx4 mfma16(short8 a, short8 b, floatx4 c) {
  return __builtin_amdgcn_mfma_f32_16x16x32_bf16(a, b, c, 0, 0, 0);
}

// ---------------------------------------------------------------------------
// Dtype detection: masks are all-ones. f32 1.0 word = 0x3F800000;
// bf16 pair = 0x3F803F80. flag: 1 = f32 storage, 0 = bf16 storage.
// ---------------------------------------------------------------------------
__global__ void det_kernel(const u32* __restrict__ mask, int* __restrict__ flag)
{
  if (threadIdx.x == 0 && blockIdx.x == 0)
    *flag = (mask[0] == 0x3F803F80u) ? 0 : 1;
}

// Generic input -> bf16 materialization (copy or f32 downconvert).
__global__ __launch_bounds__(256, 2)
void convert_kernel(const void* __restrict__ src, u16* __restrict__ dst, int n,
                    const int* __restrict__ flag)
{
  int i = blockIdx.x * 256 + threadIdx.x;
  if (i >= n) return;
  if (*flag) dst[i] = f2b(((const float*)src)[i]);
  else       dst[i] = ((const u16*)src)[i];
}

// ---------------------------------------------------------------------------
// Generic weight transpose: src[R][512] -> dst[512][dstStride], zero-padded
// rows R..dstStride.
// ---------------------------------------------------------------------------
__global__ __launch_bounds__(256, 2)
void transpose_kernel(const u16* __restrict__ S, u16* __restrict__ D,
                      int R, int dstStride, int srcZ, int dstZ)
{
  __shared__ u16 tile[64 * 72];
  const u16* src = S + (size_t)blockIdx.z * srcZ;
  u16* dst = D + (size_t)blockIdx.z * dstZ;
  const int r0 = blockIdx.x * 64, c0 = blockIdx.y * 64;
  const int t = threadIdx.x;
  const int row = t >> 2, cc = (t & 3) * 16;
  if (r0 + 64 <= R) {
    uint4 v0 = *(const uint4*)(src + (size_t)(r0 + row) * 512 + c0 + cc);
    uint4 v1 = *(const uint4*)(src + (size_t)(r0 + row) * 512 + c0 + cc + 8);
    *(uint4*)&tile[row * 72 + cc] = v0;
    *(uint4*)&tile[row * 72 + cc + 8] = v1;
  } else {
    bool ok = (r0 + row) < R;
    for (int j = 0; j < 16; j++)
      tile[row * 72 + cc + j] = ok ? src[(size_t)(r0 + row) * 512 + c0 + cc + j] : (u16)0;
  }
  __syncthreads();
  const int cl = t >> 2, rc = (t & 3) * 16;
  if (r0 + 64 <= dstStride) {
    union { uint4 v[2]; u16 u[16]; } o;
    #pragma unroll
    for (int j = 0; j < 16; j++) o.u[j] = tile[(rc + j) * 72 + cl];
    u16* gd = dst + (size_t)(c0 + cl) * dstStride + r0 + rc;
    *(uint4*)gd = o.v[0];
    *(uint4*)(gd + 8) = o.v[1];
  } else {
    for (int j = 0; j < 16; j++) {
      int rr = r0 + rc + j;
      if (rr < dstStride) dst[(size_t)(c0 + cl) * dstStride + rr] = tile[(rc + j) * 72 + cl];
    }
  }
}

// ---------------------------------------------------------------------------
// 128x128 tile MFMA GEMM, C[m][n] = sum_k A[m][k] * Bt[n][k]
// A split in K at Ksplit between (A1,lda1) and (A2,lda2); same for Bt.
// flags: 1 = scalar-guarded A loads (odd lda / K tail), 2 = transposed output
// (writes O[n][m], ld 512), 4 = A1 z-index = z/3 (stream -> modality).
// Output always ld 512, bf16.
// ---------------------------------------------------------------------------
__global__ __launch_bounds__(256, 2)
void gemm_kernel(const u16* __restrict__ A1, int lda1, int az1,
                 const u16* __restrict__ A2, int lda2, int az2,
                 const u16* __restrict__ B1, int ldb1, int bz1,
                 const u16* __restrict__ B2, int ldb2, int bz2,
                 u16* __restrict__ O, int oz,
                 int Ktot, int Ksplit, int KAvalid, int flags)
{
  __shared__ u16 gbuf[18432];
  u16* As = gbuf;          // [128][32]
  u16* Bs = gbuf + 4096;   // [128][32]

  const int z = blockIdx.z;
  const int m0 = blockIdx.x * 128, n0 = blockIdx.y * 128;
  const int t = threadIdx.x, w = t >> 6, l = t & 63, l15 = l & 15, quad = l >> 4;
  const int zA = (flags & 4) ? (z / 3) : z;
  const u16* A1p = A1 + (size_t)zA * az1;
  const u16* A2p = A2 ? (A2 + (size_t)z * az2) : nullptr;
  const u16* B1p = B1 + (size_t)z * bz1;
  const u16* B2p = B2 ? (B2 + (size_t)z * bz2) : nullptr;
  u16* Op = O + (size_t)z * oz;

  const int c0r = t >> 2;        // 0..63
  const int c0k = t & 3;         // 0..3 (8-elem chunks)

  uint4 ra[2], rb[2], ra2[2], rb2[2];

  auto gload = [&](int ks, uint4* xa, uint4* xb) {
    int k0 = ks * 32;
    bool s2 = (k0 >= Ksplit);
    const u16* Ab = s2 ? A2p : A1p;
    int la = s2 ? lda2 : lda1;
    const u16* Bb = s2 ? B2p : B1p;
    int lb = s2 ? ldb2 : ldb1;
    int kl = k0 - (s2 ? Ksplit : 0);
    for (int i = 0; i < 2; i++) {
      int row = c0r + i * 64;
      if (!(flags & 1)) {
        xa[i] = *(const uint4*)(Ab + (size_t)(m0 + row) * la + kl + c0k * 8);
      } else {
        union { uint4 v; u16 u[8]; } tmp;
        for (int j = 0; j < 8; j++) {
          int k = kl + c0k * 8 + j;
          tmp.u[j] = (k < KAvalid) ? Ab[(size_t)(m0 + row) * la + k] : (u16)0;
        }
        xa[i] = tmp.v;
      }
      xb[i] = *(const uint4*)(Bb + (size_t)(n0 + row) * lb + kl + c0k * 8);
    }
  };

  floatx4 acc[4][4];
  #pragma unroll
  for (int i = 0; i < 4; i++)
    #pragma unroll
    for (int j = 0; j < 4; j++) {
      acc[i][j][0] = 0.f; acc[i][j][1] = 0.f; acc[i][j][2] = 0.f; acc[i][j][3] = 0.f;
    }

  gload(0, ra, rb);
  const int nsteps = Ktot >> 5;
  const int mb = (w & 1) * 64, nb = (w >> 1) * 64;
  for (int ks = 0; ks < nsteps; ks++) {
    __syncthreads();
    #pragma unroll
    for (int i = 0; i < 2; i++) {
      *(uint4*)&As[(c0r + i * 64) * 32 + c0k * 8] = ra[i];
      *(uint4*)&Bs[(c0r + i * 64) * 32 + c0k * 8] = rb[i];
    }
    __syncthreads();
    if (ks + 1 < nsteps) gload(ks + 1, ra2, rb2);
    Frag fa[4], fb[4];
    #pragma unroll
    for (int i = 0; i < 4; i++) {
      fa[i].u4 = *(const uint4*)&As[(mb + i * 16 + l15) * 32 + quad * 8];
      fb[i].u4 = *(const uint4*)&Bs[(nb + i * 16 + l15) * 32 + quad * 8];
    }
    #pragma unroll
    for (int i = 0; i < 4; i++)
      #pragma unroll
      for (int j = 0; j < 4; j++)
        acc[i][j] = mfma16(fa[i].s8, fb[j].s8, acc[i][j]);
    if (ks + 1 < nsteps) {
      #pragma unroll
      for (int i = 0; i < 2; i++) { ra[i] = ra2[i]; rb[i] = rb2[i]; }
    }
  }

  if (!(flags & 2)) {
    #pragma unroll
    for (int i = 0; i < 4; i++)
      #pragma unroll
      for (int j = 0; j < 4; j++)
        #pragma unroll
        for (int rr = 0; rr < 4; rr++) {
          int gm = m0 + mb + i * 16 + quad * 4 + rr;
          int gn = n0 + nb + j * 16 + l15;
          Op[(size_t)gm * 512 + gn] = f2b(acc[i][j][rr]);
        }
  } else {
    __syncthreads();  // everyone done reading As/Bs
    u16* strip = gbuf + w * 4608;  // [64][72] per wave
    #pragma unroll
    for (int i = 0; i < 4; i++)
      #pragma unroll
      for (int j = 0; j < 4; j++)
        #pragma unroll
        for (int rr = 0; rr < 4; rr++)
          strip[(j * 16 + l15) * 72 + i * 16 + quad * 4 + rr] = f2b(acc[i][j][rr]);
    #pragma unroll
    for (int cc = 0; cc < 4; cc++) {
      uint4 v0 = *(const uint4*)&strip[l * 72 + cc * 16];
      uint4 v1 = *(const uint4*)&strip[l * 72 + cc * 16 + 8];
      u16* gd = Op + (size_t)(n0 + nb + l) * 512 + m0 + mb + cc * 16;
      *(uint4*)gd = v0;
      *(uint4*)(gd + 8) = v1;
    }
  }
}

// ---------------------------------------------------------------------------
// Row LayerNorm over 512, bf16 in/out. One wave per row.
// ---------------------------------------------------------------------------
__global__ __launch_bounds__(256, 2)
void ln_kernel(const u16* __restrict__ In, u16* __restrict__ Out,
               const u16* __restrict__ G, const u16* __restrict__ Bb,
               int inz, int outz, int gz)
{
  const int z = blockIdx.y;
  const u16* in = In + (size_t)z * inz;
  u16* out = Out + (size_t)z * outz;
  const u16* g = G + (size_t)z * gz;
  const u16* bb = Bb + (size_t)z * gz;
  const int t = threadIdx.x, w = t >> 6, l = t & 63;
  const int row = blockIdx.x * 4 + w;
  union { uint4 v; u16 u[8]; } xv, gv, bv, ov;
  xv.v = *(const uint4*)(in + (size_t)row * 512 + l * 8);
  float x[8]; float s1 = 0.f, s2 = 0.f;
  #pragma unroll
  for (int j = 0; j < 8; j++) { x[j] = b2f(xv.u[j]); s1 += x[j]; s2 += x[j] * x[j]; }
  #pragma unroll
  for (int m = 1; m < 64; m <<= 1) { s1 += __shfl_xor(s1, m); s2 += __shfl_xor(s2, m); }
  float mu = s1 * (1.0f / 512.0f);
  float var = s2 * (1.0f / 512.0f) - mu * mu;
  float rs = rsqrtf(var + 1e-5f);
  gv.v = *(const uint4*)(g + l * 8);
  bv.v = *(const uint4*)(bb + l * 8);
  #pragma unroll
  for (int j = 0; j < 8; j++) ov.u[j] = f2b((x[j] - mu) * rs * b2f(gv.u[j]) + b2f(bv.u[j]));
  *(uint4*)(out + (size_t)row * 512 + l * 8) = ov.v;
}

// ---------------------------------------------------------------------------
// Fused flash attention. One WG = 256 threads = 4 waves, handles a 128-query
// tile of one (stream, batch, head); each wave owns 32 queries so softmax
// reductions are quad shuffles only. Online softmax over 8 key-slabs of 64.
// LDS = 54,272 B. Layer 1 uses Qeff = out1 + c*q0 and mask scale (1+c):
// algebraic fold of the scores_prev recurrence (scores linear in Q; the
// returned scores include the mask term, hence the (1+c) mask scale).
// ---------------------------------------------------------------------------
__global__ __launch_bounds__(256, 2)
void flash_kernel(const u16* __restrict__ U, const u16* __restrict__ OUT,
                  u16* __restrict__ CTX,
                  const u16* __restrict__ mask_l, const u16* __restrict__ mask_v,
                  const u16* __restrict__ mask_a, const u16* __restrict__ cvec,
                  int layer)
{
  __shared__ u16 sm[27136];                // 54,272 B
  float* madd = (float*)(sm + 26112);      // [512] f32
  const int QS = 0, PO = 8704, KS = 17408, KT = 21760;  // row stride 68

  const int bx = blockIdx.x;
  const int qblk = bx & 3;
  const int rest = bx >> 2;
  const int h = rest & 7, b = (rest >> 3) & 7, s = rest >> 6;
  const int t = threadIdx.x, w = t >> 6, l = t & 63, l15 = l & 15, quad = l >> 4;

  const int qm = s / 3;                              // stream -> q modality
  const int kvmodt[9] = {0, 1, 2, 1, 0, 2, 2, 0, 1}; // stream -> kv modality
  const int km = kvmodt[s];
  const size_t SZ = (size_t)4096 * 512;

  const u16* qptr; const u16* q0ptr = nullptr; float cv = 0.f;
  if (layer == 0) {
    qptr = U + (size_t)qm * SZ;
  } else {
    qptr = OUT + (size_t)(2 * s) * SZ;
    q0ptr = U + (size_t)qm * SZ;
    cv = b2f(cvec[2 * s + 1]);
  }
  const u16* kptr = U + (size_t)km * SZ;
  const u16* mptr = (km == 0) ? mask_l : ((km == 1) ? mask_v : mask_a);
  const float msc = 1.0f + cv;

  for (int i = t; i < 512; i += 256)
    madd[i] = -1e8f * (1.0f - b2f(mptr[b * 512 + i])) * msc;

  const size_t gqbase = (size_t)b * 512 * 512 + (size_t)(qblk * 128) * 512 + h * 64;
  const size_t gkbase = (size_t)b * 512 * 512 + h * 64;

  // stage 128 Q rows (scaled by 1/8, optional + c*q0), layout [q][d] stride 68
  for (int i = 0; i < 4; i++) {
    int c = i * 256 + t, q = c >> 3, dc = c & 7;
    union { uint4 v; u16 u[8]; uint2 h2[2]; } raw, o;
    raw.v = *(const uint4*)(qptr + gqbase + (size_t)q * 512 + dc * 8);
    if (q0ptr) {
      union { uint4 v; u16 u[8]; } raw0;
      raw0.v = *(const uint4*)(q0ptr + gqbase + (size_t)q * 512 + dc * 8);
      #pragma unroll
      for (int j = 0; j < 8; j++) o.u[j] = f2b((b2f(raw.u[j]) + cv * b2f(raw0.u[j])) * 0.125f);
    } else {
      #pragma unroll
      for (int j = 0; j < 8; j++) o.u[j] = f2b(b2f(raw.u[j]) * 0.125f);
    }
    u16* dst = sm + QS + q * 68 + dc * 8;
    *(uint2*)dst = o.h2[0];
    *(uint2*)(dst + 4) = o.h2[1];
  }
  __syncthreads();

  float m_run[2], l_run[2];
  floatx4 acc[4][2];  // [dt][qt]
  #pragma unroll
  for (int i = 0; i < 2; i++) {
    m_run[i] = -1e30f; l_run[i] = 0.f;
    #pragma unroll
    for (int d = 0; d < 4; d++) { acc[d][i][0] = 0.f; acc[d][i][1] = 0.f; acc[d][i][2] = 0.f; acc[d][i][3] = 0.f; }
  }

  for (int slab = 0; slab < 8; slab++) {
    // stage K slab: Ks [kk][d] and transposed Kt [d][kk]
    for (int i = 0; i < 2; i++) {
      int c = i * 256 + t, kk = c >> 3, dc = c & 7;
      union { uint4 v; u16 u[8]; uint2 h2[2]; } raw;
      raw.v = *(const uint4*)(kptr + gkbase + (size_t)(slab * 64 + kk) * 512 + dc * 8);
      u16* ksd = sm + KS + kk * 68 + dc * 8;
      *(uint2*)ksd = raw.h2[0];
      *(uint2*)(ksd + 4) = raw.h2[1];
      #pragma unroll
      for (int j = 0; j < 8; j++) sm[KT + (dc * 8 + j) * 68 + kk] = raw.u[j];
    }
    __syncthreads();

    // phase 1: S[kk][q] = K . Q^T  (m=kk, n=q, k=d in two 32-steps)
    Frag afr[4][2], bfr[2][2];
    #pragma unroll
    for (int kt = 0; kt < 4; kt++)
      #pragma unroll
      for (int st = 0; st < 2; st++) {
        const u16* p = sm + KS + (kt * 16 + l15) * 68 + st * 32 + quad * 8;
        afr[kt][st].u2[0] = *(const uint2*)p;
        afr[kt][st].u2[1] = *(const uint2*)(p + 4);
      }
    #pragma unroll
    for (int qt = 0; qt < 2; qt++)
      #pragma unroll
      for (int st = 0; st < 2; st++) {
        const u16* p = sm + QS + (w * 32 + qt * 16 + l15) * 68 + st * 32 + quad * 8;
        bfr[qt][st].u2[0] = *(const uint2*)p;
        bfr[qt][st].u2[1] = *(const uint2*)(p + 4);
      }
    floatx4 S[2][4];
    #pragma unroll
    for (int qt = 0; qt < 2; qt++)
      #pragma unroll
      for (int kt = 0; kt < 4; kt++) {
        floatx4 zz = {0.f, 0.f, 0.f, 0.f};
        zz = mfma16(afr[kt][0].s8, bfr[qt][0].s8, zz);
        zz = mfma16(afr[kt][1].s8, bfr[qt][1].s8, zz);
        S[qt][kt] = zz;
      }
    float mdv[4][4];
    #pragma unroll
    for (int kt = 0; kt < 4; kt++)
      #pragma unroll
      for (int rr = 0; rr < 4; rr++) mdv[kt][rr] = madd[slab * 64 + kt * 16 + quad * 4 + rr];

    // online softmax per q (lane's q col = l15; quads hold different kk rows)
    #pragma unroll
    for (int qt = 0; qt < 2; qt++) {
      float mx = -1e30f;
      #pragma unroll
      for (int kt = 0; kt < 4; kt++)
        #pragma unroll
        for (int rr = 0; rr < 4; rr++) {
          S[qt][kt][rr] += mdv[kt][rr];
          mx = fmaxf(mx, S[qt][kt][rr]);
        }
      mx = fmaxf(mx, __shfl_xor(mx, 16));
      mx = fmaxf(mx, __shfl_xor(mx, 32));
      float mnew = fmaxf(m_run[qt], mx);
      float alpha = __expf(m_run[qt] - mnew);
      m_run[qt] = mnew;
      #pragma unroll
      for (int dt = 0; dt < 4; dt++)
        #pragma unroll
        for (int rr = 0; rr < 4; rr++) acc[dt][qt][rr] *= alpha;
      float ps = 0.f;
      #pragma unroll
      for (int kt = 0; kt < 4; kt++) {
        union { uint2 v; u16 u[4]; } pk;
        #pragma unroll
        for (int rr = 0; rr < 4; rr++) {
          float p = __expf(S[qt][kt][rr] - mnew);
          ps += p;
          pk.u[rr] = f2b(p);
        }
        *(uint2*)(sm + PO + (w * 32 + qt * 16 + l15) * 68 + kt * 16 + quad * 4) = pk.v;
      }
      ps += __shfl_xor(ps, 16);
      ps += __shfl_xor(ps, 32);
      l_run[qt] = l_run[qt] * alpha + ps;
    }

    // phase 3: ctx^T[d][q] += Kt . P  (m=d, n=q, k=kk in two 32-steps)
    Frag kfr[4][2], pfr[2][2];
    #pragma unroll
    for (int dt = 0; dt < 4; dt++)
      #pragma unroll
      for (int k2 = 0; k2 < 2; k2++) {
        const u16* p = sm + KT + (dt * 16 + l15) * 68 + k2 * 32 + quad * 8;
        kfr[dt][k2].u2[0] = *(const uint2*)p;
        kfr[dt][k2].u2[1] = *(const uint2*)(p + 4);
      }
    #pragma unroll
    for (int qt = 0; qt < 2; qt++)
      #pragma unroll
      for (int k2 = 0; k2 < 2; k2++) {
        const u16* p = sm + PO + (w * 32 + qt * 16 + l15) * 68 + k2 * 32 + quad * 8;
        pfr[qt][k2].u2[0] = *(const uint2*)p;
        pfr[qt][k2].u2[1] = *(const uint2*)(p + 4);
      }
    #pragma unroll
    for (int dt = 0; dt < 4; dt++)
      #pragma unroll
      for (int qt = 0; qt < 2; qt++) {
        acc[dt][qt] = mfma16(kfr[dt][0].s8, pfr[qt][0].s8, acc[dt][qt]);
        acc[dt][qt] = mfma16(kfr[dt][1].s8, pfr[qt][1].s8, acc[dt][qt]);
      }
    __syncthreads();
  }

  // epilogue: normalize by l_run; per-element stores (correctness-first)
  const size_t cbase = (size_t)s * SZ + (size_t)b * 512 * 512 + h * 64;
  #pragma unroll
  for (int qt = 0; qt < 2; qt++) {
    float rs = 1.0f / l_run[qt];
    int q = qblk * 128 + w * 32 + qt * 16 + l15;
    #pragma unroll
    for (int dt = 0; dt < 4; dt++)
      #pragma unroll
      for (int rr = 0; rr < 4; rr++) {
        int d = dt * 16 + quad * 4 + rr;
        CTX[cbase + (size_t)q * 512 + d] = f2b(acc[dt][qt][rr] * rs);
      }
  }
}

// ---------------------------------------------------------------------------
// Final feature reduction: mean & max over 1536 rows (3 row-groups x 512 q)
// per feature column. F[b][0:3072]=mean, F[b][3072:6144]=max.
// ---------------------------------------------------------------------------
__global__ __launch_bounds__(256, 2)
void feats_kernel(const u16* __restrict__ OUT, float* __restrict__ F)
{
  const int b = blockIdx.y, t = threadIdx.x;
  const int jl = t & 63, qp = t >> 6;
  const int j = blockIdx.x * 64 + jl;
  const int e = j >> 9, col = j & 511, sub = e >> 1, lay = e & 1;
  const int g0[3] = {0, 6, 3};  // row-groups: l-list, a-list, v-list streams
  float sum = 0.f, mx = -3e38f;
  for (int gi = 0; gi < 3; gi++) {
    int sid = g0[gi] + sub;
    const u16* base = OUT + ((size_t)(sid * 2 + lay) * 4096 + b * 512 + qp * 128) * 512 + col;
    #pragma unroll 8
    for (int q = 0; q < 128; q++) {
      float v = b2f(base[(size_t)q * 512]);
      sum += v;
      mx = fmaxf(mx, v);
    }
  }
  __shared__ float rsm[256], rmm[256];
  rsm[t] = sum; rmm[t] = mx;
  __syncthreads();
  if (qp == 0) {
    float ts = rsm[jl] + rsm[64 + jl] + rsm[128 + jl] + rsm[192 + jl];
    float tm = fmaxf(fmaxf(rmm[jl], rmm[64 + jl]), fmaxf(rmm[128 + jl], rmm[192 + jl]));
    F[(size_t)b * 6144 + j] = ts * (1.0f / 1536.0f);
    F[(size_t)b * 6144 + 3072 + j] = tm;
  }
}

// ---------------------------------------------------------------------------
// Classifier: out[b][c] = feats[b][:] @ clf_w[:, c]; dtype per flag.
// ---------------------------------------------------------------------------
__global__ __launch_bounds__(256, 2)
void clf_kernel(const float* __restrict__ F, const u16* __restrict__ Wc,
                void* __restrict__ OutD, const int* __restrict__ flag)
{
  const int b = blockIdx.x, t = threadIdx.x;
  float pa[9];
  #pragma unroll
  for (int c = 0; c < 9; c++) pa[c] = 0.f;
  for (int j = t; j < 6144; j += 256) {
    float f = F[(size_t)b * 6144 + j];
    #pragma unroll
    for (int c = 0; c < 9; c++) pa[c] += f * b2f(Wc[(size_t)j * 9 + c]);
  }
  __shared__ float red[9 * 256];
  #pragma unroll
  for (int c = 0; c < 9; c++) red[c * 256 + t] = pa[c];
  __syncthreads();
  for (int sft = 128; sft > 0; sft >>= 1) {
    if (t < sft) {
      #pragma unroll
      for (int c = 0; c < 9; c++) red[c * 256 + t] += red[c * 256 + t + sft];
    }
    __syncthreads();
  }
  if (t < 9) {
    if (*flag) ((float*)OutD)[b * 9 + t] = red[t * 256];
    else       ((u16*)OutD)[b * 9 + t] = f2b(red[t * 256]);
  }
}

// ---------------------------------------------------------------------------
extern "C" void kernel_launch(void* const* d_in, const int* in_sizes, int n_in,
                              void* d_out, int out_size, void* d_ws, size_t ws_size,
                              hipStream_t stream)
{
  (void)n_in; (void)out_size; (void)ws_size;
  const size_t SZ = (size_t)4096 * 512;  // elements of one [B,512,512] tensor

  u16* Wp  = (u16*)d_ws;
  u16* U   = Wp;                   // 3 SZ
  u16* Y   = U + 3 * SZ;           // 9 SZ  (pre-LN GEMM outputs)
  u16* CTX = Y + 9 * SZ;           // 9 SZ
  u16* OUTb = CTX + 9 * SZ;        // 18 SZ
  u16* BtM = OUTb + 18 * SZ;                 // 18*512*1024 (minus_w^T)
  u16* W2t = BtM + (size_t)18 * 512 * 1024;  // 18*512*512 (proj@minus_lo)^T
  u16* wlT = W2t + (size_t)18 * 512 * 512;   // 512*768
  u16* wvT = wlT + (size_t)512 * 768;        // 512*640
  u16* waT = wvT + (size_t)512 * 640;        // 512*224 (zero-padded K)
  u16* sm0 = waT + (size_t)512 * 224;
  float* F = (float*)sm0;  sm0 += (size_t)2 * 8 * 6144;  // 8x6144 f32
  int* flag = (int*)sm0;   sm0 += 2;
  u16* cml  = sm0; sm0 += 4096;
  u16* cmv  = sm0; sm0 += 4096;
  u16* cma  = sm0; sm0 += 4096;
  u16* cn1g = sm0; sm0 += 512;
  u16* cn1b = sm0; sm0 += 512;
  u16* cn2g = sm0; sm0 += 9216;
  u16* cn2b = sm0; sm0 += 9216;
  u16* ccv  = sm0; sm0 += 32;
  u16* ccw  = sm0; sm0 += 55296;
  // converted big inputs overlap later-written regions (dead before overwrite):
  u16* cl  = CTX;                  // dead after unify; CTX written by flash
  u16* cv2 = CTX + 3145728;
  u16* ca  = CTX + 5767168;
  u16* cmw = OUTb;                 // dead after transpose; OUTb written by ln2
  u16* cpw = OUTb + 9437184;       // dead after W2' GEMM
  u16* cwl = OUTb + 14155776;
  u16* cwv = cwl + 393216;
  u16* cwa = cwv + 327680;

  det_kernel<<<1, 64, 0, stream>>>((const u32*)d_in[3], flag);

  u16* cdst[17] = {cl, cv2, ca, cml, cmv, cma, cwl, cwv, cwa, cn1g, cn1b,
                   cpw, cmw, cn2g, cn2b, ccv, ccw};
  for (int i = 0; i < 17; i++) {
    int n = in_sizes[i];
    convert_kernel<<<(n + 255) / 256, 256, 0, stream>>>(d_in[i], cdst[i], n, flag);
  }

  // weight transposes (B operands in [n][k] layout)
  transpose_kernel<<<dim3(12, 8, 1), 256, 0, stream>>>(cwl, wlT, 768, 768, 0, 0);
  transpose_kernel<<<dim3(10, 8, 1), 256, 0, stream>>>(cwv, wvT, 640, 640, 0, 0);
  transpose_kernel<<<dim3(4, 8, 1), 256, 0, stream>>>(cwa, waT, 205, 224, 0, 0);
  transpose_kernel<<<dim3(16, 8, 18), 256, 0, stream>>>(cmw, BtM, 1024, 1024, 1024 * 512, 512 * 1024);

  // unify GEMMs -> Y[0..2], then LN -> U
  gemm_kernel<<<dim3(32, 4, 1), 256, 0, stream>>>(
      cl, 768, 0, nullptr, 0, 0, wlT, 768, 0, nullptr, 0, 0,
      Y, 0, 768, 768, 768, 0);
  gemm_kernel<<<dim3(32, 4, 1), 256, 0, stream>>>(
      cv2, 640, 0, nullptr, 0, 0, wvT, 640, 0, nullptr, 0, 0,
      Y + SZ, 0, 640, 640, 640, 0);
  gemm_kernel<<<dim3(32, 4, 1), 256, 0, stream>>>(
      ca, 205, 0, nullptr, 0, 0, waT, 224, 0, nullptr, 0, 0,
      Y + 2 * SZ, 0, 224, 224, 205, 1);
  ln_kernel<<<dim3(1024, 3), 256, 0, stream>>>(Y, U, cn1g, cn1b, (int)SZ, (int)SZ, 0);

  // W2'[i] = proj_w[i] @ minus_w[i][512:], stored transposed
  gemm_kernel<<<dim3(4, 4, 18), 256, 0, stream>>>(
      cpw, 512, 512 * 512, nullptr, 0, 0,
      BtM + 512, 1024, 512 * 1024, nullptr, 0, 0,
      W2t, 512 * 512, 512, 512, 512, 2);

  for (int layer = 0; layer < 2; layer++) {
    flash_kernel<<<2304, 256, 0, stream>>>(U, OUTb, CTX, cml, cmv, cma, ccv, layer);
    const u16* A1 = layer ? OUTb : U;
    int az1 = layer ? (int)(2 * SZ) : (int)SZ;
    int fl = layer ? 0 : 4;  // layer0: A1 z-index = stream/3 (modality)
    gemm_kernel<<<dim3(32, 4, 9), 256, 0, stream>>>(
        A1, 512, az1, CTX, 512, (int)SZ,
        BtM + (size_t)layer * 512 * 1024, 1024, 2 * 512 * 1024,
        W2t + (size_t)layer * 512 * 512, 512, 2 * 512 * 512,
        Y, (int)SZ, 1024, 512, 1024, fl);
    ln_kernel<<<dim3(1024, 9), 256, 0, stream>>>(
        Y, OUTb + (size_t)layer * SZ, cn2g + layer * 512, cn2b + layer * 512,
        (int)SZ, (int)(2 * SZ), 1024);
  }

  feats_kernel<<<dim3(48, 8), 256, 0, stream>>>(OUTb, F);
  clf_kernel<<<8, 256, 0, stream>>>(F, ccw, d_out, flag);
}

// Round 4
// 960.492 us; speedup vs baseline: 1.0672x; 1.0672x over previous
//
#include <hip/hip_runtime.h>
#include <cstdint>
#include <cstddef>

#define DEV __device__ __forceinline__

typedef __attribute__((ext_vector_type(8))) short short8;
typedef __attribute__((ext_vector_type(4))) float floatx4;
typedef unsigned short u16;
typedef unsigned int u32;

union Frag { short8 s8; uint4 u4; uint2 u2[2]; u16 us[8]; };

DEV float b2f(u16 u) { union { float f; u32 i; } v; v.i = ((u32)u) << 16; return v.f; }
DEV u16 f2b(float f) {
  union { float f; u32 i; } v; v.f = f; u32 x = v.i;
  return (u16)((x + 0x7fffu + ((x >> 16) & 1u)) >> 16);
}
DEV floatx4 mfma16(short8 a, short8 b, floatx4 c) {
  return __builtin_amdgcn_mfma_f32_16x16x32_bf16(a, b, c, 0, 0, 0);
}

// ---------------------------------------------------------------------------
// Dtype detection: masks are all-ones. f32 1.0 word = 0x3F800000;
// bf16 pair = 0x3F803F80. flag: 1 = f32 storage, 0 = bf16 storage.
// ---------------------------------------------------------------------------
__global__ void det_kernel(const u32* __restrict__ mask, int* __restrict__ flag)
{
  if (threadIdx.x == 0 && blockIdx.x == 0)
    *flag = (mask[0] == 0x3F803F80u) ? 0 : 1;
}

// ---------------------------------------------------------------------------
// Fused input -> bf16 materialization for all 17 inputs in ONE launch.
// Segment found by block-prefix scan (uniform scalar work).
// ---------------------------------------------------------------------------
struct ConvArgs {
  const void* src[17];
  u16* dst[17];
  int n[17];
  int bstart[17];
};

__global__ __launch_bounds__(256, 4)
void convert_all_kernel(ConvArgs a, const int* __restrict__ flag)
{
  const int bid = blockIdx.x;
  int seg = 0;
  #pragma unroll
  for (int i = 1; i < 17; i++) if (bid >= a.bstart[i]) seg = i;
  const int n = a.n[seg];
  const int base = (bid - a.bstart[seg]) * 1024 + threadIdx.x * 4;
  if (base >= n) return;
  const int f32mode = *flag;
  if (base + 4 <= n) {
    union { uint2 v; u16 u[4]; } o;
    if (f32mode) {
      const float* s = (const float*)a.src[seg] + base;
      float4 f = *(const float4*)s;
      o.u[0] = f2b(f.x); o.u[1] = f2b(f.y); o.u[2] = f2b(f.z); o.u[3] = f2b(f.w);
    } else {
      o.v = *(const uint2*)((const u16*)a.src[seg] + base);
    }
    *(uint2*)(a.dst[seg] + base) = o.v;
  } else {
    for (int k = base; k < n; k++) {
      if (f32mode) a.dst[seg][k] = f2b(((const float*)a.src[seg])[k]);
      else         a.dst[seg][k] = ((const u16*)a.src[seg])[k];
    }
  }
}

// ---------------------------------------------------------------------------
// Generic weight transpose: src[R][512] -> dst[512][dstStride], zero-padded
// rows R..dstStride.
// ---------------------------------------------------------------------------
__global__ __launch_bounds__(256, 2)
void transpose_kernel(const u16* __restrict__ S, u16* __restrict__ D,
                      int R, int dstStride, int srcZ, int dstZ)
{
  __shared__ u16 tile[64 * 72];
  const u16* src = S + (size_t)blockIdx.z * srcZ;
  u16* dst = D + (size_t)blockIdx.z * dstZ;
  const int r0 = blockIdx.x * 64, c0 = blockIdx.y * 64;
  const int t = threadIdx.x;
  const int row = t >> 2, cc = (t & 3) * 16;
  if (r0 + 64 <= R) {
    uint4 v0 = *(const uint4*)(src + (size_t)(r0 + row) * 512 + c0 + cc);
    uint4 v1 = *(const uint4*)(src + (size_t)(r0 + row) * 512 + c0 + cc + 8);
    *(uint4*)&tile[row * 72 + cc] = v0;
    *(uint4*)&tile[row * 72 + cc + 8] = v1;
  } else {
    bool ok = (r0 + row) < R;
    for (int j = 0; j < 16; j++)
      tile[row * 72 + cc + j] = ok ? src[(size_t)(r0 + row) * 512 + c0 + cc + j] : (u16)0;
  }
  __syncthreads();
  const int cl = t >> 2, rc = (t & 3) * 16;
  if (r0 + 64 <= dstStride) {
    union { uint4 v[2]; u16 u[16]; } o;
    #pragma unroll
    for (int j = 0; j < 16; j++) o.u[j] = tile[(rc + j) * 72 + cl];
    u16* gd = dst + (size_t)(c0 + cl) * dstStride + r0 + rc;
    *(uint4*)gd = o.v[0];
    *(uint4*)(gd + 8) = o.v[1];
  } else {
    for (int j = 0; j < 16; j++) {
      int rr = r0 + rc + j;
      if (rr < dstStride) dst[(size_t)(c0 + cl) * dstStride + rr] = tile[(rc + j) * 72 + cl];
    }
  }
}

// ---------------------------------------------------------------------------
// 128x128 tile MFMA GEMM, C[m][n] = sum_k A[m][k] * Bt[n][k]
// A split in K at Ksplit between (A1,lda1) and (A2,lda2); same for Bt.
// flags: 1 = scalar-guarded A loads (odd lda / K tail), 2 = transposed output
// (writes O[n][m], ld 512), 4 = A1 z-index = z/3 (stream -> modality).
// Output always ld 512, bf16. Epilogue stages through LDS for dense
// 128B-per-row dwordx4 stores (fixes 11x HBM write amplification seen in r3).
// ---------------------------------------------------------------------------
__global__ __launch_bounds__(256, 2)
void gemm_kernel(const u16* __restrict__ A1, int lda1, int az1,
                 const u16* __restrict__ A2, int lda2, int az2,
                 const u16* __restrict__ B1, int ldb1, int bz1,
                 const u16* __restrict__ B2, int ldb2, int bz2,
                 u16* __restrict__ O, int oz,
                 int Ktot, int Ksplit, int KAvalid, int flags)
{
  __shared__ u16 gbuf[18432];
  u16* As = gbuf;          // [128][32]
  u16* Bs = gbuf + 4096;   // [128][32]

  const int z = blockIdx.z;
  const int m0 = blockIdx.x * 128, n0 = blockIdx.y * 128;
  const int t = threadIdx.x, w = t >> 6, l = t & 63, l15 = l & 15, quad = l >> 4;
  const int zA = (flags & 4) ? (z / 3) : z;
  const u16* A1p = A1 + (size_t)zA * az1;
  const u16* A2p = A2 ? (A2 + (size_t)z * az2) : nullptr;
  const u16* B1p = B1 + (size_t)z * bz1;
  const u16* B2p = B2 ? (B2 + (size_t)z * bz2) : nullptr;
  u16* Op = O + (size_t)z * oz;

  const int c0r = t >> 2;        // 0..63
  const int c0k = t & 3;         // 0..3 (8-elem chunks)

  uint4 ra[2], rb[2], ra2[2], rb2[2];

  auto gload = [&](int ks, uint4* xa, uint4* xb) {
    int k0 = ks * 32;
    bool s2 = (k0 >= Ksplit);
    const u16* Ab = s2 ? A2p : A1p;
    int la = s2 ? lda2 : lda1;
    const u16* Bb = s2 ? B2p : B1p;
    int lb = s2 ? ldb2 : ldb1;
    int kl = k0 - (s2 ? Ksplit : 0);
    for (int i = 0; i < 2; i++) {
      int row = c0r + i * 64;
      if (!(flags & 1)) {
        xa[i] = *(const uint4*)(Ab + (size_t)(m0 + row) * la + kl + c0k * 8);
      } else {
        union { uint4 v; u16 u[8]; } tmp;
        for (int j = 0; j < 8; j++) {
          int k = kl + c0k * 8 + j;
          tmp.u[j] = (k < KAvalid) ? Ab[(size_t)(m0 + row) * la + k] : (u16)0;
        }
        xa[i] = tmp.v;
      }
      xb[i] = *(const uint4*)(Bb + (size_t)(n0 + row) * lb + kl + c0k * 8);
    }
  };

  floatx4 acc[4][4];
  #pragma unroll
  for (int i = 0; i < 4; i++)
    #pragma unroll
    for (int j = 0; j < 4; j++) {
      acc[i][j][0] = 0.f; acc[i][j][1] = 0.f; acc[i][j][2] = 0.f; acc[i][j][3] = 0.f;
    }

  gload(0, ra, rb);
  const int nsteps = Ktot >> 5;
  const int mb = (w & 1) * 64, nb = (w >> 1) * 64;
  for (int ks = 0; ks < nsteps; ks++) {
    __syncthreads();
    #pragma unroll
    for (int i = 0; i < 2; i++) {
      *(uint4*)&As[(c0r + i * 64) * 32 + c0k * 8] = ra[i];
      *(uint4*)&Bs[(c0r + i * 64) * 32 + c0k * 8] = rb[i];
    }
    __syncthreads();
    if (ks + 1 < nsteps) gload(ks + 1, ra2, rb2);
    Frag fa[4], fb[4];
    #pragma unroll
    for (int i = 0; i < 4; i++) {
      fa[i].u4 = *(const uint4*)&As[(mb + i * 16 + l15) * 32 + quad * 8];
      fb[i].u4 = *(const uint4*)&Bs[(nb + i * 16 + l15) * 32 + quad * 8];
    }
    #pragma unroll
    for (int i = 0; i < 4; i++)
      #pragma unroll
      for (int j = 0; j < 4; j++)
        acc[i][j] = mfma16(fa[i].s8, fb[j].s8, acc[i][j]);
    if (ks + 1 < nsteps) {
      #pragma unroll
      for (int i = 0; i < 2; i++) { ra[i] = ra2[i]; rb[i] = rb2[i]; }
    }
  }

  __syncthreads();  // everyone done reading As/Bs; reuse gbuf for epilogue
  u16* strip = gbuf + w * 4608;  // [64][72] per wave
  if (!(flags & 2)) {
    // stage wave's 64x64 tile (m-local x n-local), then dense row stores
    #pragma unroll
    for (int i = 0; i < 4; i++)
      #pragma unroll
      for (int j = 0; j < 4; j++)
        #pragma unroll
        for (int rr = 0; rr < 4; rr++)
          strip[(i * 16 + quad * 4 + rr) * 72 + j * 16 + l15] = f2b(acc[i][j][rr]);
    const int row = l >> 3, cc = l & 7;   // 8 lanes/row, 8 u16 each
    #pragma unroll
    for (int i = 0; i < 8; i++) {
      uint4 v = *(const uint4*)&strip[(i * 8 + row) * 72 + cc * 8];
      *(uint4*)(Op + (size_t)(m0 + mb + i * 8 + row) * 512 + n0 + nb + cc * 8) = v;
    }
  } else {
    #pragma unroll
    for (int i = 0; i < 4; i++)
      #pragma unroll
      for (int j = 0; j < 4; j++)
        #pragma unroll
        for (int rr = 0; rr < 4; rr++)
          strip[(j * 16 + l15) * 72 + i * 16 + quad * 4 + rr] = f2b(acc[i][j][rr]);
    const int row = l >> 3, cc = l & 7;
    #pragma unroll
    for (int i = 0; i < 8; i++) {
      uint4 v = *(const uint4*)&strip[(i * 8 + row) * 72 + cc * 8];
      *(uint4*)(Op + (size_t)(n0 + nb + i * 8 + row) * 512 + m0 + mb + cc * 8) = v;
    }
  }
}

// ---------------------------------------------------------------------------
// Row LayerNorm over 512, bf16 in/out. One wave per row.
// ---------------------------------------------------------------------------
__global__ __launch_bounds__(256, 2)
void ln_kernel(const u16* __restrict__ In, u16* __restrict__ Out,
               const u16* __restrict__ G, const u16* __restrict__ Bb,
               int inz, int outz, int gz)
{
  const int z = blockIdx.y;
  const u16* in = In + (size_t)z * inz;
  u16* out = Out + (size_t)z * outz;
  const u16* g = G + (size_t)z * gz;
  const u16* bb = Bb + (size_t)z * gz;
  const int t = threadIdx.x, w = t >> 6, l = t & 63;
  const int row = blockIdx.x * 4 + w;
  union { uint4 v; u16 u[8]; } xv, gv, bv, ov;
  xv.v = *(const uint4*)(in + (size_t)row * 512 + l * 8);
  float x[8]; float s1 = 0.f, s2 = 0.f;
  #pragma unroll
  for (int j = 0; j < 8; j++) { x[j] = b2f(xv.u[j]); s1 += x[j]; s2 += x[j] * x[j]; }
  #pragma unroll
  for (int m = 1; m < 64; m <<= 1) { s1 += __shfl_xor(s1, m); s2 += __shfl_xor(s2, m); }
  float mu = s1 * (1.0f / 512.0f);
  float var = s2 * (1.0f / 512.0f) - mu * mu;
  float rs = rsqrtf(var + 1e-5f);
  gv.v = *(const uint4*)(g + l * 8);
  bv.v = *(const uint4*)(bb + l * 8);
  #pragma unroll
  for (int j = 0; j < 8; j++) ov.u[j] = f2b((x[j] - mu) * rs * b2f(gv.u[j]) + b2f(bv.u[j]));
  *(uint4*)(out + (size_t)row * 512 + l * 8) = ov.v;
}

// ---------------------------------------------------------------------------
// Fused flash attention. One WG = 256 threads = 4 waves, handles a 128-query
// tile of one (stream, batch, head); each wave owns 32 queries so softmax
// reductions are quad shuffles only. Online softmax over 8 key-slabs of 64.
// LDS = 54,272 B. Layer 1 uses Qeff = out1 + c*q0 and mask scale (1+c):
// algebraic fold of the scores_prev recurrence (scores linear in Q).
// Epilogue stages ctx through wave-private LDS for dense 128B-row stores.
// ---------------------------------------------------------------------------
__global__ __launch_bounds__(256, 2)
void flash_kernel(const u16* __restrict__ U, const u16* __restrict__ OUT,
                  u16* __restrict__ CTX,
                  const u16* __restrict__ mask_l, const u16* __restrict__ mask_v,
                  const u16* __restrict__ mask_a, const u16* __restrict__ cvec,
                  int layer)
{
  __shared__ u16 sm[27136];                // 54,272 B
  float* madd = (float*)(sm + 26112);      // [512] f32
  const int QS = 0, PO = 8704, KS = 17408, KT = 21760;  // row stride 68

  const int bx = blockIdx.x;
  const int qblk = bx & 3;
  const int rest = bx >> 2;
  const int h = rest & 7, b = (rest >> 3) & 7, s = rest >> 6;
  const int t = threadIdx.x, w = t >> 6, l = t & 63, l15 = l & 15, quad = l >> 4;

  const int qm = s / 3;                              // stream -> q modality
  const int kvmodt[9] = {0, 1, 2, 1, 0, 2, 2, 0, 1}; // stream -> kv modality
  const int km = kvmodt[s];
  const size_t SZ = (size_t)4096 * 512;

  const u16* qptr; const u16* q0ptr = nullptr; float cv = 0.f;
  if (layer == 0) {
    qptr = U + (size_t)qm * SZ;
  } else {
    qptr = OUT + (size_t)(2 * s) * SZ;
    q0ptr = U + (size_t)qm * SZ;
    cv = b2f(cvec[2 * s + 1]);
  }
  const u16* kptr = U + (size_t)km * SZ;
  const u16* mptr = (km == 0) ? mask_l : ((km == 1) ? mask_v : mask_a);
  const float msc = 1.0f + cv;

  for (int i = t; i < 512; i += 256)
    madd[i] = -1e8f * (1.0f - b2f(mptr[b * 512 + i])) * msc;

  const size_t gqbase = (size_t)b * 512 * 512 + (size_t)(qblk * 128) * 512 + h * 64;
  const size_t gkbase = (size_t)b * 512 * 512 + h * 64;

  // stage 128 Q rows (scaled by 1/8, optional + c*q0), layout [q][d] stride 68
  for (int i = 0; i < 4; i++) {
    int c = i * 256 + t, q = c >> 3, dc = c & 7;
    union { uint4 v; u16 u[8]; uint2 h2[2]; } raw, o;
    raw.v = *(const uint4*)(qptr + gqbase + (size_t)q * 512 + dc * 8);
    if (q0ptr) {
      union { uint4 v; u16 u[8]; } raw0;
      raw0.v = *(const uint4*)(q0ptr + gqbase + (size_t)q * 512 + dc * 8);
      #pragma unroll
      for (int j = 0; j < 8; j++) o.u[j] = f2b((b2f(raw.u[j]) + cv * b2f(raw0.u[j])) * 0.125f);
    } else {
      #pragma unroll
      for (int j = 0; j < 8; j++) o.u[j] = f2b(b2f(raw.u[j]) * 0.125f);
    }
    u16* dst = sm + QS + q * 68 + dc * 8;
    *(uint2*)dst = o.h2[0];
    *(uint2*)(dst + 4) = o.h2[1];
  }
  __syncthreads();

  float m_run[2], l_run[2];
  floatx4 acc[4][2];  // [dt][qt]
  #pragma unroll
  for (int i = 0; i < 2; i++) {
    m_run[i] = -1e30f; l_run[i] = 0.f;
    #pragma unroll
    for (int d = 0; d < 4; d++) { acc[d][i][0] = 0.f; acc[d][i][1] = 0.f; acc[d][i][2] = 0.f; acc[d][i][3] = 0.f; }
  }

  for (int slab = 0; slab < 8; slab++) {
    // stage K slab: Ks [kk][d] and transposed Kt [d][kk]
    for (int i = 0; i < 2; i++) {
      int c = i * 256 + t, kk = c >> 3, dc = c & 7;
      union { uint4 v; u16 u[8]; uint2 h2[2]; } raw;
      raw.v = *(const uint4*)(kptr + gkbase + (size_t)(slab * 64 + kk) * 512 + dc * 8);
      u16* ksd = sm + KS + kk * 68 + dc * 8;
      *(uint2*)ksd = raw.h2[0];
      *(uint2*)(ksd + 4) = raw.h2[1];
      #pragma unroll
      for (int j = 0; j < 8; j++) sm[KT + (dc * 8 + j) * 68 + kk] = raw.u[j];
    }
    __syncthreads();

    // phase 1: S[kk][q] = K . Q^T  (m=kk, n=q, k=d in two 32-steps)
    Frag afr[4][2], bfr[2][2];
    #pragma unroll
    for (int kt = 0; kt < 4; kt++)
      #pragma unroll
      for (int st = 0; st < 2; st++) {
        const u16* p = sm + KS + (kt * 16 + l15) * 68 + st * 32 + quad * 8;
        afr[kt][st].u2[0] = *(const uint2*)p;
        afr[kt][st].u2[1] = *(const uint2*)(p + 4);
      }
    #pragma unroll
    for (int qt = 0; qt < 2; qt++)
      #pragma unroll
      for (int st = 0; st < 2; st++) {
        const u16* p = sm + QS + (w * 32 + qt * 16 + l15) * 68 + st * 32 + quad * 8;
        bfr[qt][st].u2[0] = *(const uint2*)p;
        bfr[qt][st].u2[1] = *(const uint2*)(p + 4);
      }
    floatx4 S[2][4];
    #pragma unroll
    for (int qt = 0; qt < 2; qt++)
      #pragma unroll
      for (int kt = 0; kt < 4; kt++) {
        floatx4 zz = {0.f, 0.f, 0.f, 0.f};
        zz = mfma16(afr[kt][0].s8, bfr[qt][0].s8, zz);
        zz = mfma16(afr[kt][1].s8, bfr[qt][1].s8, zz);
        S[qt][kt] = zz;
      }
    float mdv[4][4];
    #pragma unroll
    for (int kt = 0; kt < 4; kt++)
      #pragma unroll
      for (int rr = 0; rr < 4; rr++) mdv[kt][rr] = madd[slab * 64 + kt * 16 + quad * 4 + rr];

    // online softmax per q (lane's q col = l15; quads hold different kk rows)
    #pragma unroll
    for (int qt = 0; qt < 2; qt++) {
      float mx = -1e30f;
      #pragma unroll
      for (int kt = 0; kt < 4; kt++)
        #pragma unroll
        for (int rr = 0; rr < 4; rr++) {
          S[qt][kt][rr] += mdv[kt][rr];
          mx = fmaxf(mx, S[qt][kt][rr]);
        }
      mx = fmaxf(mx, __shfl_xor(mx, 16));
      mx = fmaxf(mx, __shfl_xor(mx, 32));
      float mnew = fmaxf(m_run[qt], mx);
      float alpha = __expf(m_run[qt] - mnew);
      m_run[qt] = mnew;
      #pragma unroll
      for (int dt = 0; dt < 4; dt++)
        #pragma unroll
        for (int rr = 0; rr < 4; rr++) acc[dt][qt][rr] *= alpha;
      float ps = 0.f;
      #pragma unroll
      for (int kt = 0; kt < 4; kt++) {
        union { uint2 v; u16 u[4]; } pk;
        #pragma unroll
        for (int rr = 0; rr < 4; rr++) {
          float p = __expf(S[qt][kt][rr] - mnew);
          ps += p;
          pk.u[rr] = f2b(p);
        }
        *(uint2*)(sm + PO + (w * 32 + qt * 16 + l15) * 68 + kt * 16 + quad * 4) = pk.v;
      }
      ps += __shfl_xor(ps, 16);
      ps += __shfl_xor(ps, 32);
      l_run[qt] = l_run[qt] * alpha + ps;
    }

    // phase 3: ctx^T[d][q] += Kt . P  (m=d, n=q, k=kk in two 32-steps)
    Frag kfr[4][2], pfr[2][2];
    #pragma unroll
    for (int dt = 0; dt < 4; dt++)
      #pragma unroll
      for (int k2 = 0; k2 < 2; k2++) {
        const u16* p = sm + KT + (dt * 16 + l15) * 68 + k2 * 32 + quad * 8;
        kfr[dt][k2].u2[0] = *(const uint2*)p;
        kfr[dt][k2].u2[1] = *(const uint2*)(p + 4);
      }
    #pragma unroll
    for (int qt = 0; qt < 2; qt++)
      #pragma unroll
      for (int k2 = 0; k2 < 2; k2++) {
        const u16* p = sm + PO + (w * 32 + qt * 16 + l15) * 68 + k2 * 32 + quad * 8;
        pfr[qt][k2].u2[0] = *(const uint2*)p;
        pfr[qt][k2].u2[1] = *(const uint2*)(p + 4);
      }
    #pragma unroll
    for (int dt = 0; dt < 4; dt++)
      #pragma unroll
      for (int qt = 0; qt < 2; qt++) {
        acc[dt][qt] = mfma16(kfr[dt][0].s8, pfr[qt][0].s8, acc[dt][qt]);
        acc[dt][qt] = mfma16(kfr[dt][1].s8, pfr[qt][1].s8, acc[dt][qt]);
      }
    __syncthreads();
  }

  // epilogue: normalize by l_run; stage [16 q][64 d] per wave in LDS, then
  // dense stores (4 lanes x 32B = 128B per q-row).
  u16* strip = sm + KS + w * 2176;  // wave-private (stage->read within wave)
  const size_t cbase = (size_t)s * SZ + (size_t)b * 512 * 512 + h * 64;
  #pragma unroll
  for (int qt = 0; qt < 2; qt++) {
    float rs = 1.0f / l_run[qt];
    #pragma unroll
    for (int dt = 0; dt < 4; dt++) {
      union { uint2 v; u16 u[4]; } pk;
      #pragma unroll
      for (int rr = 0; rr < 4; rr++) pk.u[rr] = f2b(acc[dt][qt][rr] * rs);
      *(uint2*)(strip + l15 * 68 + dt * 16 + quad * 4) = pk.v;
    }
    const int row = l >> 2, cc = l & 3;
    const u16* sp = strip + row * 68 + cc * 16;
    uint4 v0 = *(const uint4*)sp;
    uint4 v1 = *(const uint4*)(sp + 8);
    int q = qblk * 128 + w * 32 + qt * 16 + row;
    u16* gd = CTX + cbase + (size_t)q * 512 + cc * 16;
    *(uint4*)gd = v0;
    *(uint4*)(gd + 8) = v1;
  }
}

// ---------------------------------------------------------------------------
// Final feature reduction: mean & max over 1536 rows (3 row-groups x 512 q)
// per feature column. F[b][0:3072]=mean, F[b][3072:6144]=max.
// ---------------------------------------------------------------------------
__global__ __launch_bounds__(256, 2)
void feats_kernel(const u16* __restrict__ OUT, float* __restrict__ F)
{
  const int b = blockIdx.y, t = threadIdx.x;
  const int jl = t & 63, qp = t >> 6;
  const int j = blockIdx.x * 64 + jl;
  const int e = j >> 9, col = j & 511, sub = e >> 1, lay = e & 1;
  const int g0[3] = {0, 6, 3};  // row-groups: l-list, a-list, v-list streams
  float sum = 0.f, mx = -3e38f;
  for (int gi = 0; gi < 3; gi++) {
    int sid = g0[gi] + sub;
    const u16* base = OUT + ((size_t)(sid * 2 + lay) * 4096 + b * 512 + qp * 128) * 512 + col;
    #pragma unroll 8
    for (int q = 0; q < 128; q++) {
      float v = b2f(base[(size_t)q * 512]);
      sum += v;
      mx = fmaxf(mx, v);
    }
  }
  __shared__ float rsm[256], rmm[256];
  rsm[t] = sum; rmm[t] = mx;
  __syncthreads();
  if (qp == 0) {
    float ts = rsm[jl] + rsm[64 + jl] + rsm[128 + jl] + rsm[192 + jl];
    float tm = fmaxf(fmaxf(rmm[jl], rmm[64 + jl]), fmaxf(rmm[128 + jl], rmm[192 + jl]));
    F[(size_t)b * 6144 + j] = ts * (1.0f / 1536.0f);
    F[(size_t)b * 6144 + 3072 + j] = tm;
  }
}

// ---------------------------------------------------------------------------
// Classifier: out[b][c] = feats[b][:] @ clf_w[:, c]; dtype per flag.
// ---------------------------------------------------------------------------
__global__ __launch_bounds__(256, 2)
void clf_kernel(const float* __restrict__ F, const u16* __restrict__ Wc,
                void* __restrict__ OutD, const int* __restrict__ flag)
{
  const int b = blockIdx.x, t = threadIdx.x;
  float pa[9];
  #pragma unroll
  for (int c = 0; c < 9; c++) pa[c] = 0.f;
  for (int j = t; j < 6144; j += 256) {
    float f = F[(size_t)b * 6144 + j];
    #pragma unroll
    for (int c = 0; c < 9; c++) pa[c] += f * b2f(Wc[(size_t)j * 9 + c]);
  }
  __shared__ float red[9 * 256];
  #pragma unroll
  for (int c = 0; c < 9; c++) red[c * 256 + t] = pa[c];
  __syncthreads();
  for (int sft = 128; sft > 0; sft >>= 1) {
    if (t < sft) {
      #pragma unroll
      for (int c = 0; c < 9; c++) red[c * 256 + t] += red[c * 256 + t + sft];
    }
    __syncthreads();
  }
  if (t < 9) {
    if (*flag) ((float*)OutD)[b * 9 + t] = red[t * 256];
    else       ((u16*)OutD)[b * 9 + t] = f2b(red[t * 256]);
  }
}

// ---------------------------------------------------------------------------
extern "C" void kernel_launch(void* const* d_in, const int* in_sizes, int n_in,
                              void* d_out, int out_size, void* d_ws, size_t ws_size,
                              hipStream_t stream)
{
  (void)n_in; (void)out_size; (void)ws_size;
  const size_t SZ = (size_t)4096 * 512;  // elements of one [B,512,512] tensor

  u16* Wp  = (u16*)d_ws;
  u16* U   = Wp;                   // 3 SZ
  u16* Y   = U + 3 * SZ;           // 9 SZ  (pre-LN GEMM outputs)
  u16* CTX = Y + 9 * SZ;           // 9 SZ
  u16* OUTb = CTX + 9 * SZ;        // 18 SZ
  u16* BtM = OUTb + 18 * SZ;                 // 18*512*1024 (minus_w^T)
  u16* W2t = BtM + (size_t)18 * 512 * 1024;  // 18*512*512 (proj@minus_lo)^T
  u16* wlT = W2t + (size_t)18 * 512 * 512;   // 512*768
  u16* wvT = wlT + (size_t)512 * 768;        // 512*640
  u16* waT = wvT + (size_t)512 * 640;        // 512*224 (zero-padded K)
  u16* sm0 = waT + (size_t)512 * 224;
  float* F = (float*)sm0;  sm0 += (size_t)2 * 8 * 6144;  // 8x6144 f32
  int* flag = (int*)sm0;   sm0 += 2;
  u16* cml  = sm0; sm0 += 4096;
  u16* cmv  = sm0; sm0 += 4096;
  u16* cma  = sm0; sm0 += 4096;
  u16* cn1g = sm0; sm0 += 512;
  u16* cn1b = sm0; sm0 += 512;
  u16* cn2g = sm0; sm0 += 9216;
  u16* cn2b = sm0; sm0 += 9216;
  u16* ccv  = sm0; sm0 += 32;
  u16* ccw  = sm0; sm0 += 55296;
  // converted big inputs overlap later-written regions (dead before overwrite):
  u16* cl  = CTX;                  // dead after unify; CTX written by flash
  u16* cv2 = CTX + 3145728;
  u16* ca  = CTX + 5767168;
  u16* cmw = OUTb;                 // dead after transpose; OUTb written by ln2
  u16* cpw = OUTb + 9437184;       // dead after W2' GEMM
  u16* cwl = OUTb + 14155776;
  u16* cwv = cwl + 393216;
  u16* cwa = cwv + 327680;

  det_kernel<<<1, 64, 0, stream>>>((const u32*)d_in[3], flag);

  // single fused convert launch
  ConvArgs ca_args;
  u16* cdst[17] = {cl, cv2, ca, cml, cmv, cma, cwl, cwv, cwa, cn1g, cn1b,
                   cpw, cmw, cn2g, cn2b, ccv, ccw};
  int btot = 0;
  for (int i = 0; i < 17; i++) {
    ca_args.src[i] = d_in[i];
    ca_args.dst[i] = cdst[i];
    ca_args.n[i] = in_sizes[i];
    ca_args.bstart[i] = btot;
    btot += (in_sizes[i] + 1023) / 1024;
  }
  convert_all_kernel<<<btot, 256, 0, stream>>>(ca_args, flag);

  // weight transposes (B operands in [n][k] layout)
  transpose_kernel<<<dim3(12, 8, 1), 256, 0, stream>>>(cwl, wlT, 768, 768, 0, 0);
  transpose_kernel<<<dim3(10, 8, 1), 256, 0, stream>>>(cwv, wvT, 640, 640, 0, 0);
  transpose_kernel<<<dim3(4, 8, 1), 256, 0, stream>>>(cwa, waT, 205, 224, 0, 0);
  transpose_kernel<<<dim3(16, 8, 18), 256, 0, stream>>>(cmw, BtM, 1024, 1024, 1024 * 512, 512 * 1024);

  // unify GEMMs -> Y[0..2], then LN -> U
  gemm_kernel<<<dim3(32, 4, 1), 256, 0, stream>>>(
      cl, 768, 0, nullptr, 0, 0, wlT, 768, 0, nullptr, 0, 0,
      Y, 0, 768, 768, 768, 0);
  gemm_kernel<<<dim3(32, 4, 1), 256, 0, stream>>>(
      cv2, 640, 0, nullptr, 0, 0, wvT, 640, 0, nullptr, 0, 0,
      Y + SZ, 0, 640, 640, 640, 0);
  gemm_kernel<<<dim3(32, 4, 1), 256, 0, stream>>>(
      ca, 205, 0, nullptr, 0, 0, waT, 224, 0, nullptr, 0, 0,
      Y + 2 * SZ, 0, 224, 224, 205, 1);
  ln_kernel<<<dim3(1024, 3), 256, 0, stream>>>(Y, U, cn1g, cn1b, (int)SZ, (int)SZ, 0);

  // W2'[i] = proj_w[i] @ minus_w[i][512:], stored transposed
  gemm_kernel<<<dim3(4, 4, 18), 256, 0, stream>>>(
      cpw, 512, 512 * 512, nullptr, 0, 0,
      BtM + 512, 1024, 512 * 1024, nullptr, 0, 0,
      W2t, 512 * 512, 512, 512, 512, 2);

  for (int layer = 0; layer < 2; layer++) {
    flash_kernel<<<2304, 256, 0, stream>>>(U, OUTb, CTX, cml, cmv, cma, ccv, layer);
    const u16* A1 = layer ? OUTb : U;
    int az1 = layer ? (int)(2 * SZ) : (int)SZ;
    int fl = layer ? 0 : 4;  // layer0: A1 z-index = stream/3 (modality)
    gemm_kernel<<<dim3(32, 4, 9), 256, 0, stream>>>(
        A1, 512, az1, CTX, 512, (int)SZ,
        BtM + (size_t)layer * 512 * 1024, 1024, 2 * 512 * 1024,
        W2t + (size_t)layer * 512 * 512, 512, 2 * 512 * 512,
        Y, (int)SZ, 1024, 512, 1024, fl);
    ln_kernel<<<dim3(1024, 9), 256, 0, stream>>>(
        Y, OUTb + (size_t)layer * SZ, cn2g + layer * 512, cn2b + layer * 512,
        (int)SZ, (int)(2 * SZ), 1024);
  }

  feats_kernel<<<dim3(48, 8), 256, 0, stream>>>(OUTb, F);
  clf_kernel<<<8, 256, 0, stream>>>(F, ccw, d_out, flag);
}

// Round 5
// 602.024 us; speedup vs baseline: 1.7027x; 1.5954x over previous
//
#include <hip/hip_runtime.h>
#include <cstdint>
#include <cstddef>

#define DEV __device__ __forceinline__

typedef __attribute__((ext_vector_type(8))) short short8;
typedef __attribute__((ext_vector_type(4))) float floatx4;
typedef unsigned short u16;
typedef unsigned int u32;

union Frag { short8 s8; uint4 u4; uint2 u2[2]; u16 us[8]; };

DEV float b2f(u16 u) { union { float f; u32 i; } v; v.i = ((u32)u) << 16; return v.f; }
DEV u16 f2b(float f) {
  union { float f; u32 i; } v; v.f = f; u32 x = v.i;
  return (u16)((x + 0x7fffu + ((x >> 16) & 1u)) >> 16);
}
DEV floatx4 mfma16(short8 a, short8 b, floatx4 c) {
  return __builtin_amdgcn_mfma_f32_16x16x32_bf16(a, b, c, 0, 0, 0);
}
// async global->LDS, 16B per lane; LDS dest = wave-uniform base + lane*16
DEV void gl_lds16(const u16* g, u16* l) {
  __builtin_amdgcn_global_load_lds(
      (const __attribute__((address_space(1))) void*)g,
      (__attribute__((address_space(3))) void*)l, 16, 0, 0);
}

// ---------------------------------------------------------------------------
// Dtype detection: masks are all-ones. f32 1.0 word = 0x3F800000;
// bf16 pair = 0x3F803F80. flag: 1 = f32 storage, 0 = bf16 storage.
// ---------------------------------------------------------------------------
__global__ void det_kernel(const u32* __restrict__ mask, int* __restrict__ flag)
{
  if (threadIdx.x == 0 && blockIdx.x == 0)
    *flag = (mask[0] == 0x3F803F80u) ? 0 : 1;
}

// ---------------------------------------------------------------------------
// Fused input -> bf16 materialization for all 17 inputs in ONE launch.
// ---------------------------------------------------------------------------
struct ConvArgs {
  const void* src[17];
  u16* dst[17];
  int n[17];
  int bstart[17];
};

__global__ __launch_bounds__(256, 4)
void convert_all_kernel(ConvArgs a, const int* __restrict__ flag)
{
  const int bid = blockIdx.x;
  int seg = 0;
  #pragma unroll
  for (int i = 1; i < 17; i++) if (bid >= a.bstart[i]) seg = i;
  const int n = a.n[seg];
  const int base = (bid - a.bstart[seg]) * 1024 + threadIdx.x * 4;
  if (base >= n) return;
  const int f32mode = *flag;
  if (base + 4 <= n) {
    union { uint2 v; u16 u[4]; } o;
    if (f32mode) {
      const float* s = (const float*)a.src[seg] + base;
      float4 f = *(const float4*)s;
      o.u[0] = f2b(f.x); o.u[1] = f2b(f.y); o.u[2] = f2b(f.z); o.u[3] = f2b(f.w);
    } else {
      o.v = *(const uint2*)((const u16*)a.src[seg] + base);
    }
    *(uint2*)(a.dst[seg] + base) = o.v;
  } else {
    for (int k = base; k < n; k++) {
      if (f32mode) a.dst[seg][k] = f2b(((const float*)a.src[seg])[k]);
      else         a.dst[seg][k] = ((const u16*)a.src[seg])[k];
    }
  }
}

// ---------------------------------------------------------------------------
// Generic weight transpose: src[R][512] -> dst[512][dstStride], zero-padded
// rows R..dstStride.
// ---------------------------------------------------------------------------
__global__ __launch_bounds__(256, 2)
void transpose_kernel(const u16* __restrict__ S, u16* __restrict__ D,
                      int R, int dstStride, int srcZ, int dstZ)
{
  __shared__ u16 tile[64 * 72];
  const u16* src = S + (size_t)blockIdx.z * srcZ;
  u16* dst = D + (size_t)blockIdx.z * dstZ;
  const int r0 = blockIdx.x * 64, c0 = blockIdx.y * 64;
  const int t = threadIdx.x;
  const int row = t >> 2, cc = (t & 3) * 16;
  if (r0 + 64 <= R) {
    uint4 v0 = *(const uint4*)(src + (size_t)(r0 + row) * 512 + c0 + cc);
    uint4 v1 = *(const uint4*)(src + (size_t)(r0 + row) * 512 + c0 + cc + 8);
    *(uint4*)&tile[row * 72 + cc] = v0;
    *(uint4*)&tile[row * 72 + cc + 8] = v1;
  } else {
    bool ok = (r0 + row) < R;
    for (int j = 0; j < 16; j++)
      tile[row * 72 + cc + j] = ok ? src[(size_t)(r0 + row) * 512 + c0 + cc + j] : (u16)0;
  }
  __syncthreads();
  const int cl = t >> 2, rc = (t & 3) * 16;
  if (r0 + 64 <= dstStride) {
    union { uint4 v[2]; u16 u[16]; } o;
    #pragma unroll
    for (int j = 0; j < 16; j++) o.u[j] = tile[(rc + j) * 72 + cl];
    u16* gd = dst + (size_t)(c0 + cl) * dstStride + r0 + rc;
    *(uint4*)gd = o.v[0];
    *(uint4*)(gd + 8) = o.v[1];
  } else {
    for (int j = 0; j < 16; j++) {
      int rr = r0 + rc + j;
      if (rr < dstStride) dst[(size_t)(c0 + cl) * dstStride + rr] = tile[(rc + j) * 72 + cl];
    }
  }
}

// ---------------------------------------------------------------------------
// 128x128 tile MFMA GEMM, C[m][n] = sum_k A[m][k] * Bt[n][k]
// m97-style K loop: 2 barriers + width-16 global_load_lds staging (no VGPR
// round trip). A split in K at Ksplit between (A1,lda1)/(A2,lda2); same for B.
// flags: 1 = guarded VGPR A loads (K tail), 2 = transposed output, 4 = A1
// z-index = z/3. Output ld 512, bf16, LDS-staged dense stores.
// ---------------------------------------------------------------------------
__global__ __launch_bounds__(256, 4)
void gemm_kernel(const u16* __restrict__ A1, int lda1, int az1,
                 const u16* __restrict__ A2, int lda2, int az2,
                 const u16* __restrict__ B1, int ldb1, int bz1,
                 const u16* __restrict__ B2, int ldb2, int bz2,
                 u16* __restrict__ O, int oz,
                 int Ktot, int Ksplit, int KAvalid, int flags)
{
  __shared__ u16 gbuf[18432];
  u16* As = gbuf;          // [128][32]
  u16* Bs = gbuf + 4096;   // [128][32]

  const int z = blockIdx.z;
  const int m0 = blockIdx.x * 128, n0 = blockIdx.y * 128;
  const int t = threadIdx.x, w = t >> 6, l = t & 63, l15 = l & 15, quad = l >> 4;
  const int zA = (flags & 4) ? (z / 3) : z;
  const u16* A1p = A1 + (size_t)zA * az1;
  const u16* A2p = A2 ? (A2 + (size_t)z * az2) : nullptr;
  const u16* B1p = B1 + (size_t)z * bz1;
  const u16* B2p = B2 ? (B2 + (size_t)z * bz2) : nullptr;
  u16* Op = O + (size_t)z * oz;

  const int c0r = t >> 2;        // 0..63 (row within half-tile)
  const int c0k = t & 3;         // 8-elem chunk in k
  u16* AsW = As + (size_t)t * 8; // lane-contiguous: byte offset t*16
  u16* BsW = Bs + (size_t)t * 8;

  floatx4 acc[4][4];
  #pragma unroll
  for (int i = 0; i < 4; i++)
    #pragma unroll
    for (int j = 0; j < 4; j++) {
      acc[i][j][0] = 0.f; acc[i][j][1] = 0.f; acc[i][j][2] = 0.f; acc[i][j][3] = 0.f;
    }

  const int nsteps = Ktot >> 5;
  const int mb = (w & 1) * 64, nb = (w >> 1) * 64;
  for (int ks = 0; ks < nsteps; ks++) {
    const int k0 = ks * 32;
    const bool s2 = (k0 >= Ksplit);
    const u16* Ab = s2 ? A2p : A1p;
    const int la = s2 ? lda2 : lda1;
    const u16* Bb = s2 ? B2p : B1p;
    const int lb = s2 ? ldb2 : ldb1;
    const int kl = k0 - (s2 ? Ksplit : 0);
    const u16* ga0 = Ab + (size_t)(m0 + c0r) * la + kl + c0k * 8;
    const u16* ga1 = Ab + (size_t)(m0 + c0r + 64) * la + kl + c0k * 8;
    const u16* gb0 = Bb + (size_t)(n0 + c0r) * lb + kl + c0k * 8;
    const u16* gb1 = Bb + (size_t)(n0 + c0r + 64) * lb + kl + c0k * 8;

    __syncthreads();  // prior compute done reading LDS
    gl_lds16(gb0, BsW);
    gl_lds16(gb1, BsW + 2048);
    if (!(flags & 1)) {
      gl_lds16(ga0, AsW);
      gl_lds16(ga1, AsW + 2048);
    } else {
      union { uint4 v; u16 u[8]; } tA[2];
      #pragma unroll
      for (int i = 0; i < 2; i++) {
        const u16* gp = i ? ga1 : ga0;
        for (int j = 0; j < 8; j++) {
          int k = kl + c0k * 8 + j;
          tA[i].u[j] = (k < KAvalid) ? gp[j] : (u16)0;
        }
      }
      *(uint4*)AsW = tA[0].v;
      *(uint4*)(AsW + 2048) = tA[1].v;
    }
    __syncthreads();  // drains vmcnt: DMA landed

    Frag fa[4], fb[4];
    #pragma unroll
    for (int i = 0; i < 4; i++) {
      fa[i].u4 = *(const uint4*)&As[(mb + i * 16 + l15) * 32 + quad * 8];
      fb[i].u4 = *(const uint4*)&Bs[(nb + i * 16 + l15) * 32 + quad * 8];
    }
    #pragma unroll
    for (int i = 0; i < 4; i++)
      #pragma unroll
      for (int j = 0; j < 4; j++)
        acc[i][j] = mfma16(fa[i].s8, fb[j].s8, acc[i][j]);
  }

  __syncthreads();  // everyone done reading As/Bs; reuse gbuf for epilogue
  u16* strip = gbuf + w * 4608;  // [64][72] per wave
  if (!(flags & 2)) {
    #pragma unroll
    for (int i = 0; i < 4; i++)
      #pragma unroll
      for (int j = 0; j < 4; j++)
        #pragma unroll
        for (int rr = 0; rr < 4; rr++)
          strip[(i * 16 + quad * 4 + rr) * 72 + j * 16 + l15] = f2b(acc[i][j][rr]);
    const int row = l >> 3, cc = l & 7;   // 8 lanes/row, 8 u16 each
    #pragma unroll
    for (int i = 0; i < 8; i++) {
      uint4 v = *(const uint4*)&strip[(i * 8 + row) * 72 + cc * 8];
      *(uint4*)(Op + (size_t)(m0 + mb + i * 8 + row) * 512 + n0 + nb + cc * 8) = v;
    }
  } else {
    #pragma unroll
    for (int i = 0; i < 4; i++)
      #pragma unroll
      for (int j = 0; j < 4; j++)
        #pragma unroll
        for (int rr = 0; rr < 4; rr++)
          strip[(j * 16 + l15) * 72 + i * 16 + quad * 4 + rr] = f2b(acc[i][j][rr]);
    const int row = l >> 3, cc = l & 7;
    #pragma unroll
    for (int i = 0; i < 8; i++) {
      uint4 v = *(const uint4*)&strip[(i * 8 + row) * 72 + cc * 8];
      *(uint4*)(Op + (size_t)(n0 + nb + i * 8 + row) * 512 + m0 + mb + cc * 8) = v;
    }
  }
}

// ---------------------------------------------------------------------------
// Row LayerNorm over 512, bf16 in/out. One wave per row.
// ---------------------------------------------------------------------------
__global__ __launch_bounds__(256, 2)
void ln_kernel(const u16* __restrict__ In, u16* __restrict__ Out,
               const u16* __restrict__ G, const u16* __restrict__ Bb,
               int inz, int outz, int gz)
{
  const int z = blockIdx.y;
  const u16* in = In + (size_t)z * inz;
  u16* out = Out + (size_t)z * outz;
  const u16* g = G + (size_t)z * gz;
  const u16* bb = Bb + (size_t)z * gz;
  const int t = threadIdx.x, w = t >> 6, l = t & 63;
  const int row = blockIdx.x * 4 + w;
  union { uint4 v; u16 u[8]; } xv, gv, bv, ov;
  xv.v = *(const uint4*)(in + (size_t)row * 512 + l * 8);
  float x[8]; float s1 = 0.f, s2 = 0.f;
  #pragma unroll
  for (int j = 0; j < 8; j++) { x[j] = b2f(xv.u[j]); s1 += x[j]; s2 += x[j] * x[j]; }
  #pragma unroll
  for (int m = 1; m < 64; m <<= 1) { s1 += __shfl_xor(s1, m); s2 += __shfl_xor(s2, m); }
  float mu = s1 * (1.0f / 512.0f);
  float var = s2 * (1.0f / 512.0f) - mu * mu;
  float rs = rsqrtf(var + 1e-5f);
  gv.v = *(const uint4*)(g + l * 8);
  bv.v = *(const uint4*)(bb + l * 8);
  #pragma unroll
  for (int j = 0; j < 8; j++) ov.u[j] = f2b((x[j] - mu) * rs * b2f(gv.u[j]) + b2f(bv.u[j]));
  *(uint4*)(out + (size_t)row * 512 + l * 8) = ov.v;
}

// ---------------------------------------------------------------------------
// Fused flash attention. One WG = 256 threads = 4 waves, 128-query tile of one
// (stream, batch, head); each wave owns 32 queries (softmax = quad shuffles).
// Online softmax over 8 key-slabs of 64. LDS = 53,248 B -> 3 blocks/CU.
// Layer 1 uses Qeff = out1 + c*q0 and mask scale (1+c) (scores linear in Q).
// ---------------------------------------------------------------------------
__global__ __launch_bounds__(256, 2)
void flash_kernel(const u16* __restrict__ U, const u16* __restrict__ OUT,
                  u16* __restrict__ CTX,
                  const u16* __restrict__ mask_l, const u16* __restrict__ mask_v,
                  const u16* __restrict__ mask_a, const u16* __restrict__ cvec,
                  int layer)
{
  __shared__ u16 sm[26624];                // 53,248 B (<160/3 KiB -> 3 blk/CU)
  u16* madd = sm + 26112;                  // [512] bf16 mask-add
  const int QS = 0, PO = 8704, KS = 17408, KT = 21760;  // row stride 68

  const int bx = blockIdx.x;
  const int qblk = bx & 3;
  const int rest = bx >> 2;
  const int h = rest & 7, b = (rest >> 3) & 7, s = rest >> 6;
  const int t = threadIdx.x, w = t >> 6, l = t & 63, l15 = l & 15, quad = l >> 4;

  const int qm = s / 3;                              // stream -> q modality
  const int kvmodt[9] = {0, 1, 2, 1, 0, 2, 2, 0, 1}; // stream -> kv modality
  const int km = kvmodt[s];
  const size_t SZ = (size_t)4096 * 512;

  const u16* qptr; const u16* q0ptr = nullptr; float cv = 0.f;
  if (layer == 0) {
    qptr = U + (size_t)qm * SZ;
  } else {
    qptr = OUT + (size_t)(2 * s) * SZ;
    q0ptr = U + (size_t)qm * SZ;
    cv = b2f(cvec[2 * s + 1]);
  }
  const u16* kptr = U + (size_t)km * SZ;
  const u16* mptr = (km == 0) ? mask_l : ((km == 1) ? mask_v : mask_a);
  const float msc = 1.0f + cv;

  for (int i = t; i < 512; i += 256)
    madd[i] = f2b(-1e8f * (1.0f - b2f(mptr[b * 512 + i])) * msc);

  const size_t gqbase = (size_t)b * 512 * 512 + (size_t)(qblk * 128) * 512 + h * 64;
  const size_t gkbase = (size_t)b * 512 * 512 + h * 64;

  // stage 128 Q rows (scaled by 1/8, optional + c*q0), layout [q][d] stride 68
  for (int i = 0; i < 4; i++) {
    int c = i * 256 + t, q = c >> 3, dc = c & 7;
    union { uint4 v; u16 u[8]; uint2 h2[2]; } raw, o;
    raw.v = *(const uint4*)(qptr + gqbase + (size_t)q * 512 + dc * 8);
    if (q0ptr) {
      union { uint4 v; u16 u[8]; } raw0;
      raw0.v = *(const uint4*)(q0ptr + gqbase + (size_t)q * 512 + dc * 8);
      #pragma unroll
      for (int j = 0; j < 8; j++) o.u[j] = f2b((b2f(raw.u[j]) + cv * b2f(raw0.u[j])) * 0.125f);
    } else {
      #pragma unroll
      for (int j = 0; j < 8; j++) o.u[j] = f2b(b2f(raw.u[j]) * 0.125f);
    }
    u16* dst = sm + QS + q * 68 + dc * 8;
    *(uint2*)dst = o.h2[0];
    *(uint2*)(dst + 4) = o.h2[1];
  }
  __syncthreads();

  float m_run[2], l_run[2];
  floatx4 acc[4][2];  // [dt][qt]
  #pragma unroll
  for (int i = 0; i < 2; i++) {
    m_run[i] = -1e30f; l_run[i] = 0.f;
    #pragma unroll
    for (int d = 0; d < 4; d++) { acc[d][i][0] = 0.f; acc[d][i][1] = 0.f; acc[d][i][2] = 0.f; acc[d][i][3] = 0.f; }
  }

  for (int slab = 0; slab < 8; slab++) {
    // stage K slab: Ks [kk][d] and transposed Kt [d][kk]
    for (int i = 0; i < 2; i++) {
      int c = i * 256 + t, kk = c >> 3, dc = c & 7;
      union { uint4 v; u16 u[8]; uint2 h2[2]; } raw;
      raw.v = *(const uint4*)(kptr + gkbase + (size_t)(slab * 64 + kk) * 512 + dc * 8);
      u16* ksd = sm + KS + kk * 68 + dc * 8;
      *(uint2*)ksd = raw.h2[0];
      *(uint2*)(ksd + 4) = raw.h2[1];
      #pragma unroll
      for (int j = 0; j < 8; j++) sm[KT + (dc * 8 + j) * 68 + kk] = raw.u[j];
    }
    __syncthreads();

    // phase 1: S[kk][q] = K . Q^T  (m=kk, n=q, k=d in two 32-steps)
    Frag afr[4][2], bfr[2][2];
    #pragma unroll
    for (int kt = 0; kt < 4; kt++)
      #pragma unroll
      for (int st = 0; st < 2; st++) {
        const u16* p = sm + KS + (kt * 16 + l15) * 68 + st * 32 + quad * 8;
        afr[kt][st].u2[0] = *(const uint2*)p;
        afr[kt][st].u2[1] = *(const uint2*)(p + 4);
      }
    #pragma unroll
    for (int qt = 0; qt < 2; qt++)
      #pragma unroll
      for (int st = 0; st < 2; st++) {
        const u16* p = sm + QS + (w * 32 + qt * 16 + l15) * 68 + st * 32 + quad * 8;
        bfr[qt][st].u2[0] = *(const uint2*)p;
        bfr[qt][st].u2[1] = *(const uint2*)(p + 4);
      }
    floatx4 S[2][4];
    #pragma unroll
    for (int qt = 0; qt < 2; qt++)
      #pragma unroll
      for (int kt = 0; kt < 4; kt++) {
        floatx4 zz = {0.f, 0.f, 0.f, 0.f};
        zz = mfma16(afr[kt][0].s8, bfr[qt][0].s8, zz);
        zz = mfma16(afr[kt][1].s8, bfr[qt][1].s8, zz);
        S[qt][kt] = zz;
      }
    float mdv[4][4];
    #pragma unroll
    for (int kt = 0; kt < 4; kt++)
      #pragma unroll
      for (int rr = 0; rr < 4; rr++) mdv[kt][rr] = b2f(madd[slab * 64 + kt * 16 + quad * 4 + rr]);

    // online softmax per q (lane's q col = l15; quads hold different kk rows)
    #pragma unroll
    for (int qt = 0; qt < 2; qt++) {
      float mx = -1e30f;
      #pragma unroll
      for (int kt = 0; kt < 4; kt++)
        #pragma unroll
        for (int rr = 0; rr < 4; rr++) {
          S[qt][kt][rr] += mdv[kt][rr];
          mx = fmaxf(mx, S[qt][kt][rr]);
        }
      mx = fmaxf(mx, __shfl_xor(mx, 16));
      mx = fmaxf(mx, __shfl_xor(mx, 32));
      float mnew = fmaxf(m_run[qt], mx);
      float alpha = __expf(m_run[qt] - mnew);
      m_run[qt] = mnew;
      #pragma unroll
      for (int dt = 0; dt < 4; dt++)
        #pragma unroll
        for (int rr = 0; rr < 4; rr++) acc[dt][qt][rr] *= alpha;
      float ps = 0.f;
      #pragma unroll
      for (int kt = 0; kt < 4; kt++) {
        union { uint2 v; u16 u[4]; } pk;
        #pragma unroll
        for (int rr = 0; rr < 4; rr++) {
          float p = __expf(S[qt][kt][rr] - mnew);
          ps += p;
          pk.u[rr] = f2b(p);
        }
        *(uint2*)(sm + PO + (w * 32 + qt * 16 + l15) * 68 + kt * 16 + quad * 4) = pk.v;
      }
      ps += __shfl_xor(ps, 16);
      ps += __shfl_xor(ps, 32);
      l_run[qt] = l_run[qt] * alpha + ps;
    }

    // phase 3: ctx^T[d][q] += Kt . P  (m=d, n=q, k=kk in two 32-steps)
    Frag kfr[4][2], pfr[2][2];
    #pragma unroll
    for (int dt = 0; dt < 4; dt++)
      #pragma unroll
      for (int k2 = 0; k2 < 2; k2++) {
        const u16* p = sm + KT + (dt * 16 + l15) * 68 + k2 * 32 + quad * 8;
        kfr[dt][k2].u2[0] = *(const uint2*)p;
        kfr[dt][k2].u2[1] = *(const uint2*)(p + 4);
      }
    #pragma unroll
    for (int qt = 0; qt < 2; qt++)
      #pragma unroll
      for (int k2 = 0; k2 < 2; k2++) {
        const u16* p = sm + PO + (w * 32 + qt * 16 + l15) * 68 + k2 * 32 + quad * 8;
        pfr[qt][k2].u2[0] = *(const uint2*)p;
        pfr[qt][k2].u2[1] = *(const uint2*)(p + 4);
      }
    #pragma unroll
    for (int dt = 0; dt < 4; dt++)
      #pragma unroll
      for (int qt = 0; qt < 2; qt++) {
        acc[dt][qt] = mfma16(kfr[dt][0].s8, pfr[qt][0].s8, acc[dt][qt]);
        acc[dt][qt] = mfma16(kfr[dt][1].s8, pfr[qt][1].s8, acc[dt][qt]);
      }
    __syncthreads();
  }

  // epilogue: normalize by l_run; stage [16 q][64 d] per wave in LDS, then
  // dense stores (4 lanes x 32B = 128B per q-row).
  u16* strip = sm + KS + w * 2176;  // wave-private (stage->read within wave)
  const size_t cbase = (size_t)s * SZ + (size_t)b * 512 * 512 + h * 64;
  #pragma unroll
  for (int qt = 0; qt < 2; qt++) {
    float rs = 1.0f / l_run[qt];
    #pragma unroll
    for (int dt = 0; dt < 4; dt++) {
      union { uint2 v; u16 u[4]; } pk;
      #pragma unroll
      for (int rr = 0; rr < 4; rr++) pk.u[rr] = f2b(acc[dt][qt][rr] * rs);
      *(uint2*)(strip + l15 * 68 + dt * 16 + quad * 4) = pk.v;
    }
    const int row = l >> 2, cc = l & 3;
    const u16* sp = strip + row * 68 + cc * 16;
    uint4 v0 = *(const uint4*)sp;
    uint4 v1 = *(const uint4*)(sp + 8);
    int q = qblk * 128 + w * 32 + qt * 16 + row;
    u16* gd = CTX + cbase + (size_t)q * 512 + cc * 16;
    *(uint4*)gd = v0;
    *(uint4*)(gd + 8) = v1;
  }
}

// ---------------------------------------------------------------------------
// Final feature reduction: mean & max over 1536 rows (3 row-groups x 512 q)
// per feature column. F[b][0:3072]=mean, F[b][3072:6144]=max.
// ---------------------------------------------------------------------------
__global__ __launch_bounds__(256, 2)
void feats_kernel(const u16* __restrict__ OUT, float* __restrict__ F)
{
  const int b = blockIdx.y, t = threadIdx.x;
  const int jl = t & 63, qp = t >> 6;
  const int j = blockIdx.x * 64 + jl;
  const int e = j >> 9, col = j & 511, sub = e >> 1, lay = e & 1;
  const int g0[3] = {0, 6, 3};  // row-groups: l-list, a-list, v-list streams
  float sum = 0.f, mx = -3e38f;
  for (int gi = 0; gi < 3; gi++) {
    int sid = g0[gi] + sub;
    const u16* base = OUT + ((size_t)(sid * 2 + lay) * 4096 + b * 512 + qp * 128) * 512 + col;
    #pragma unroll 8
    for (int q = 0; q < 128; q++) {
      float v = b2f(base[(size_t)q * 512]);
      sum += v;
      mx = fmaxf(mx, v);
    }
  }
  __shared__ float rsm[256], rmm[256];
  rsm[t] = sum; rmm[t] = mx;
  __syncthreads();
  if (qp == 0) {
    float ts = rsm[jl] + rsm[64 + jl] + rsm[128 + jl] + rsm[192 + jl];
    float tm = fmaxf(fmaxf(rmm[jl], rmm[64 + jl]), fmaxf(rmm[128 + jl], rmm[192 + jl]));
    F[(size_t)b * 6144 + j] = ts * (1.0f / 1536.0f);
    F[(size_t)b * 6144 + 3072 + j] = tm;
  }
}

// ---------------------------------------------------------------------------
// Classifier: out[b][c] = feats[b][:] @ clf_w[:, c]; dtype per flag.
// ---------------------------------------------------------------------------
__global__ __launch_bounds__(256, 2)
void clf_kernel(const float* __restrict__ F, const u16* __restrict__ Wc,
                void* __restrict__ OutD, const int* __restrict__ flag)
{
  const int b = blockIdx.x, t = threadIdx.x;
  float pa[9];
  #pragma unroll
  for (int c = 0; c < 9; c++) pa[c] = 0.f;
  for (int j = t; j < 6144; j += 256) {
    float f = F[(size_t)b * 6144 + j];
    #pragma unroll
    for (int c = 0; c < 9; c++) pa[c] += f * b2f(Wc[(size_t)j * 9 + c]);
  }
  __shared__ float red[9 * 256];
  #pragma unroll
  for (int c = 0; c < 9; c++) red[c * 256 + t] = pa[c];
  __syncthreads();
  for (int sft = 128; sft > 0; sft >>= 1) {
    if (t < sft) {
      #pragma unroll
      for (int c = 0; c < 9; c++) red[c * 256 + t] += red[c * 256 + t + sft];
    }
    __syncthreads();
  }
  if (t < 9) {
    if (*flag) ((float*)OutD)[b * 9 + t] = red[t * 256];
    else       ((u16*)OutD)[b * 9 + t] = f2b(red[t * 256]);
  }
}

// ---------------------------------------------------------------------------
extern "C" void kernel_launch(void* const* d_in, const int* in_sizes, int n_in,
                              void* d_out, int out_size, void* d_ws, size_t ws_size,
                              hipStream_t stream)
{
  (void)n_in; (void)out_size; (void)ws_size;
  const size_t SZ = (size_t)4096 * 512;  // elements of one [B,512,512] tensor

  u16* Wp  = (u16*)d_ws;
  u16* U   = Wp;                   // 3 SZ
  u16* Y   = U + 3 * SZ;           // 9 SZ  (pre-LN GEMM outputs)
  u16* CTX = Y + 9 * SZ;           // 9 SZ
  u16* OUTb = CTX + 9 * SZ;        // 18 SZ
  u16* BtM = OUTb + 18 * SZ;                 // 18*512*1024 (minus_w^T)
  u16* W2t = BtM + (size_t)18 * 512 * 1024;  // 18*512*512 (proj@minus_lo)^T
  u16* wlT = W2t + (size_t)18 * 512 * 512;   // 512*768
  u16* wvT = wlT + (size_t)512 * 768;        // 512*640
  u16* waT = wvT + (size_t)512 * 640;        // 512*224 (zero-padded K)
  u16* sm0 = waT + (size_t)512 * 224;
  float* F = (float*)sm0;  sm0 += (size_t)2 * 8 * 6144;  // 8x6144 f32
  int* flag = (int*)sm0;   sm0 += 2;
  u16* cml  = sm0; sm0 += 4096;
  u16* cmv  = sm0; sm0 += 4096;
  u16* cma  = sm0; sm0 += 4096;
  u16* cn1g = sm0; sm0 += 512;
  u16* cn1b = sm0; sm0 += 512;
  u16* cn2g = sm0; sm0 += 9216;
  u16* cn2b = sm0; sm0 += 9216;
  u16* ccv  = sm0; sm0 += 32;
  u16* ccw  = sm0; sm0 += 55296;
  // converted big inputs overlap later-written regions (dead before overwrite):
  u16* cl  = CTX;                  // dead after unify; CTX written by flash
  u16* cv2 = CTX + 3145728;
  u16* ca  = CTX + 5767168;
  u16* cmw = OUTb;                 // dead after transpose; OUTb written by ln2
  u16* cpw = OUTb + 9437184;       // dead after W2' GEMM
  u16* cwl = OUTb + 14155776;
  u16* cwv = cwl + 393216;
  u16* cwa = cwv + 327680;

  det_kernel<<<1, 64, 0, stream>>>((const u32*)d_in[3], flag);

  // single fused convert launch
  ConvArgs ca_args;
  u16* cdst[17] = {cl, cv2, ca, cml, cmv, cma, cwl, cwv, cwa, cn1g, cn1b,
                   cpw, cmw, cn2g, cn2b, ccv, ccw};
  int btot = 0;
  for (int i = 0; i < 17; i++) {
    ca_args.src[i] = d_in[i];
    ca_args.dst[i] = cdst[i];
    ca_args.n[i] = in_sizes[i];
    ca_args.bstart[i] = btot;
    btot += (in_sizes[i] + 1023) / 1024;
  }
  convert_all_kernel<<<btot, 256, 0, stream>>>(ca_args, flag);

  // weight transposes (B operands in [n][k] layout)
  transpose_kernel<<<dim3(12, 8, 1), 256, 0, stream>>>(cwl, wlT, 768, 768, 0, 0);
  transpose_kernel<<<dim3(10, 8, 1), 256, 0, stream>>>(cwv, wvT, 640, 640, 0, 0);
  transpose_kernel<<<dim3(4, 8, 1), 256, 0, stream>>>(cwa, waT, 205, 224, 0, 0);
  transpose_kernel<<<dim3(16, 8, 18), 256, 0, stream>>>(cmw, BtM, 1024, 1024, 1024 * 512, 512 * 1024);

  // unify GEMMs -> Y[0..2], then LN -> U
  gemm_kernel<<<dim3(32, 4, 1), 256, 0, stream>>>(
      cl, 768, 0, nullptr, 0, 0, wlT, 768, 0, nullptr, 0, 0,
      Y, 0, 768, 768, 768, 0);
  gemm_kernel<<<dim3(32, 4, 1), 256, 0, stream>>>(
      cv2, 640, 0, nullptr, 0, 0, wvT, 640, 0, nullptr, 0, 0,
      Y + SZ, 0, 640, 640, 640, 0);
  gemm_kernel<<<dim3(32, 4, 1), 256, 0, stream>>>(
      ca, 205, 0, nullptr, 0, 0, waT, 224, 0, nullptr, 0, 0,
      Y + 2 * SZ, 0, 224, 224, 205, 1);
  ln_kernel<<<dim3(1024, 3), 256, 0, stream>>>(Y, U, cn1g, cn1b, (int)SZ, (int)SZ, 0);

  // W2'[i] = proj_w[i] @ minus_w[i][512:], stored transposed
  gemm_kernel<<<dim3(4, 4, 18), 256, 0, stream>>>(
      cpw, 512, 512 * 512, nullptr, 0, 0,
      BtM + 512, 1024, 512 * 1024, nullptr, 0, 0,
      W2t, 512 * 512, 512, 512, 512, 2);

  for (int layer = 0; layer < 2; layer++) {
    flash_kernel<<<2304, 256, 0, stream>>>(U, OUTb, CTX, cml, cmv, cma, ccv, layer);
    const u16* A1 = layer ? OUTb : U;
    int az1 = layer ? (int)(2 * SZ) : (int)SZ;
    int fl = layer ? 0 : 4;  // layer0: A1 z-index = stream/3 (modality)
    gemm_kernel<<<dim3(32, 4, 9), 256, 0, stream>>>(
        A1, 512, az1, CTX, 512, (int)SZ,
        BtM + (size_t)layer * 512 * 1024, 1024, 2 * 512 * 1024,
        W2t + (size_t)layer * 512 * 512, 512, 2 * 512 * 512,
        Y, (int)SZ, 1024, 512, 1024, fl);
    ln_kernel<<<dim3(1024, 9), 256, 0, stream>>>(
        Y, OUTb + (size_t)layer * SZ, cn2g + layer * 512, cn2b + layer * 512,
        (int)SZ, (int)(2 * SZ), 1024);
  }

  feats_kernel<<<dim3(48, 8), 256, 0, stream>>>(OUTb, F);
  clf_kernel<<<8, 256, 0, stream>>>(F, ccw, d_out, flag);
}